// Round 13
// baseline (383.176 us; speedup 1.0000x reference)
//
#include <hip/hip_runtime.h>
#include <hip/hip_bf16.h>

#define B_    2
#define S_    2048
#define DIM_  2048
#define H_    16
#define HKV_  4
#define D_    128
#define NQKV_ 3072
#define BS_   (B_*S_)

typedef __attribute__((ext_vector_type(8))) short short8;
typedef __attribute__((ext_vector_type(4))) float f32x4;

__device__ __forceinline__ unsigned short f2bf(float f) {
    union { float f; unsigned u; } v; v.f = f;
    unsigned r = (v.u + 0x7fffu + ((v.u >> 16) & 1u)) >> 16;
    return (unsigned short)r;
}
__device__ __forceinline__ float bf2f(unsigned short h) {
    union { unsigned u; float f; } v; v.u = ((unsigned)h) << 16;
    return v.f;
}

// ---------------- convert x (fp32 -> bf16), vectorized ----------------
__global__ void k_convert(const float* __restrict__ in, unsigned short* __restrict__ out, int n4) {
    int i = blockIdx.x * blockDim.x + threadIdx.x;
    if (i >= n4) return;
    float4 v = ((const float4*)in)[i];
    union { unsigned short us[4]; unsigned long long u; } o;
    o.us[0] = f2bf(v.x); o.us[1] = f2bf(v.y); o.us[2] = f2bf(v.z); o.us[3] = f2bf(v.w);
    ((unsigned long long*)out)[i] = o.u;
}

// ------------- transpose fp32 [K][N] -> bf16 [N][K] -------------------
__global__ void k_transpose(const float* __restrict__ W, unsigned short* __restrict__ WT,
                            int K, int N) {
    __shared__ float tile[64][65];
    const int k0 = blockIdx.x * 64, n0 = blockIdx.y * 64;
    const int tx = threadIdx.x & 63, ty = threadIdx.x >> 6;
    #pragma unroll
    for (int i = 0; i < 64; i += 4)
        tile[ty + i][tx] = W[(size_t)(k0 + ty + i) * N + n0 + tx];
    __syncthreads();
    #pragma unroll
    for (int i = 0; i < 64; i += 4)
        WT[(size_t)(n0 + ty + i) * K + k0 + tx] = f2bf(tile[tx][ty + i]);
}

// ------------- GEMM: C[M][N] = A[M][K] * BT[N][K]^T  (bf16 MFMA) ------
// 128x128 tile, BK=64, 4 waves (2x2), 64x64/wave. XCD bijective swizzle.
template<typename OUT_T>
__global__ __launch_bounds__(256, 2)
void k_gemm_bt(const unsigned short* __restrict__ A,
               const unsigned short* __restrict__ BT,
               OUT_T* __restrict__ C, int M, int N, int K)
{
    __shared__ unsigned short lds_a[128 * 64];
    __shared__ unsigned short lds_b[128 * 64];
    const int tid  = threadIdx.x;
    const int nbn  = N >> 7;
    const int nwg  = gridDim.x;
    const int orig = blockIdx.x;
    const int q8   = nwg >> 3, r8 = nwg & 7;
    const int xcd  = orig & 7, lid = orig >> 3;
    const int wgid = (xcd < r8 ? xcd * (q8 + 1) : r8 * (q8 + 1) + (xcd - r8) * q8) + lid;
    const int bm   = wgid / nbn, bn = wgid % nbn;
    const int row0 = bm << 7, col0 = bn << 7;
    const int lane = tid & 63, wave = tid >> 6;
    const int wr = wave >> 1, wc = wave & 1;
    const int lg = lane >> 4, lr = lane & 15;

    f32x4 acc[4][4] = {};

    for (int kt = 0; kt < K; kt += 64) {
        __syncthreads();
        #pragma unroll
        for (int issue = 0; issue < 4; ++issue) {
            int e = issue * 2048 + wave * 512 + lane * 8;
            int r = e >> 6, kk = e & 63;
            const unsigned short* srcA = A  + (size_t)(row0 + r) * K + kt + kk;
            const unsigned short* srcB = BT + (size_t)(col0 + r) * K + kt + kk;
            unsigned short* dstA = lds_a + issue * 2048 + wave * 512;
            unsigned short* dstB = lds_b + issue * 2048 + wave * 512;
            __builtin_amdgcn_global_load_lds(
                (const __attribute__((address_space(1))) void*)srcA,
                (__attribute__((address_space(3))) void*)dstA, 16, 0, 0);
            __builtin_amdgcn_global_load_lds(
                (const __attribute__((address_space(1))) void*)srcB,
                (__attribute__((address_space(3))) void*)dstB, 16, 0, 0);
        }
        __syncthreads();
        #pragma unroll
        for (int kc = 0; kc < 2; ++kc) {
            short8 af[4], bf[4];
            #pragma unroll
            for (int m = 0; m < 4; ++m)
                af[m] = *(const short8*)&lds_a[(wr * 64 + m * 16 + lr) * 64 + kc * 32 + lg * 8];
            #pragma unroll
            for (int n = 0; n < 4; ++n)
                bf[n] = *(const short8*)&lds_b[(wc * 64 + n * 16 + lr) * 64 + kc * 32 + lg * 8];
            #pragma unroll
            for (int m = 0; m < 4; ++m)
                #pragma unroll
                for (int n = 0; n < 4; ++n)
                    acc[m][n] = __builtin_amdgcn_mfma_f32_16x16x32_bf16(af[m], bf[n], acc[m][n], 0, 0, 0);
        }
    }

    #pragma unroll
    for (int m = 0; m < 4; ++m)
        #pragma unroll
        for (int n = 0; n < 4; ++n)
            #pragma unroll
            for (int j = 0; j < 4; ++j) {
                int row = row0 + wr * 64 + m * 16 + lg * 4 + j;
                int col = col0 + wc * 64 + n * 16 + lr;
                if constexpr (sizeof(OUT_T) == 2)
                    C[(size_t)row * N + col] = (OUT_T)f2bf(acc[m][n][j]);
                else
                    C[(size_t)row * N + col] = (OUT_T)acc[m][n][j];
            }
}

// ------------------------- RoPE on Q and K (in-place) -----------------
__global__ void k_rope(unsigned short* __restrict__ qkv) {
    const int pair = blockIdx.x * 256 + threadIdx.x;
    const int row  = blockIdx.y;
    const int s    = row & (S_ - 1);
    const int col  = pair * 2;
    const int t    = (col & 127) >> 1;
    const float theta = exp2f(-((float)(2 * t) / 128.0f) * 9.965784284662087f);
    const float ang = (float)s * theta;
    const float sn = sinf(ang), cs = cosf(ang);
    unsigned short* p = qkv + (size_t)row * NQKV_ + col;
    float x1 = bf2f(p[0]), x2 = bf2f(p[1]);
    p[0] = f2bf(x1 * cs - x2 * sn);
    p[1] = f2bf(x1 * sn + x2 * cs);
}

// --------- transpose V out of qkv: vt[(b*4+hk)][d][s] (bf16) ----------
__global__ void k_vtrans(const unsigned short* __restrict__ qkv, unsigned short* __restrict__ vt) {
    __shared__ unsigned short tile[64][65];
    const int s0 = blockIdx.x * 64;
    const int d0 = blockIdx.y * 64;
    const int bh = blockIdx.z;
    const int b = bh >> 2, hk = bh & 3;
    const int tx = threadIdx.x & 63, ty = threadIdx.x >> 6;
    #pragma unroll
    for (int i = 0; i < 64; i += 4)
        tile[i + ty][tx] = qkv[(size_t)(b * S_ + s0 + i + ty) * NQKV_ + (DIM_ + 512) + hk * D_ + d0 + tx];
    __syncthreads();
    #pragma unroll
    for (int i = 0; i < 64; i += 4)
        vt[((size_t)bh * D_ + d0 + i + ty) * S_ + s0 + tx] = tile[tx][i + ty];
}

// --------------------------- flash attention --------------------------
// grid 1024 linear; 4 waves/block; one 64-row q-tile per block.
// Bijective L->(qt,h,b) with w-flip so co-resident blocks pair (qt,31-qt):
// per-CU work uniform (66 tile-units). 4 blocks/CU (143KB LDS) -> block-level
// overlap hides stage/softmax stalls. Swapped QK^T + in-register softmax.
#define KPAD 136   // 128 + 8
#define VPAD 72    // 64 + 8
#define SCALE2 0.12751739f   // (1/sqrt(128)) * log2(e)

#define STAGE_LOAD(K0) do {                                                                    \
    ks0 = *(const short8*)(kglob + (size_t)((K0) + (tid >> 4)) * NQKV_ + (tid & 15) * 8);      \
    ks1 = *(const short8*)(kglob + (size_t)((K0) + 16 + (tid >> 4)) * NQKV_ + (tid & 15) * 8); \
    ks2 = *(const short8*)(kglob + (size_t)((K0) + 32 + (tid >> 4)) * NQKV_ + (tid & 15) * 8); \
    ks3 = *(const short8*)(kglob + (size_t)((K0) + 48 + (tid >> 4)) * NQKV_ + (tid & 15) * 8); \
    vs0 = *(const short8*)(vglob + (size_t)(tid >> 3) * S_ + (K0) + (tid & 7) * 8);            \
    vs1 = *(const short8*)(vglob + (size_t)(32 + (tid >> 3)) * S_ + (K0) + (tid & 7) * 8);     \
    vs2 = *(const short8*)(vglob + (size_t)(64 + (tid >> 3)) * S_ + (K0) + (tid & 7) * 8);     \
    vs3 = *(const short8*)(vglob + (size_t)(96 + (tid >> 3)) * S_ + (K0) + (tid & 7) * 8);     \
} while (0)

__global__ __launch_bounds__(256, 4)
void k_attn(const unsigned short* __restrict__ qkv,
            const unsigned short* __restrict__ vt,
            unsigned short* __restrict__ o)
{
    __shared__ unsigned short k_lds[64 * KPAD];    // 17408 B
    __shared__ unsigned short v_lds[128 * VPAD];   // 18432 B

    const int L   = blockIdx.x;
    const int w4  = L >> 8;                  // 0..3
    const int c   = L & 255;
    const int qt0 = c & 31;
    const int hb  = (c >> 5) | (w4 << 3);    // 0..31
    const int h   = hb & 15, b = hb >> 4;
    const int qt  = (w4 & 1) ? (31 - qt0) : qt0;   // pair (qt,31-qt) per CU
    const int hk  = h >> 2;

    const int tid = threadIdx.x;
    const int lane = tid & 63, wave = tid >> 6;    // 4 waves
    const int lg = lane >> 4, lr = lane & 15;
    const int q_base = qt * 64 + wave * 16;

    // Q fragments (B-operand of swapped QK^T)
    short8 qf[4];
    {
        const unsigned short* qrow = qkv + (size_t)(b * S_ + q_base + lr) * NQKV_ + h * D_;
        #pragma unroll
        for (int dc = 0; dc < 4; ++dc)
            qf[dc] = *(const short8*)(qrow + dc * 32 + lg * 8);
    }

    float m_run = -1e30f, l_run = 0.f;
    f32x4 oacc[8] = {};

    const unsigned short* kglob = qkv + (size_t)(b * S_) * NQKV_ + DIM_ + hk * D_;
    const unsigned short* vglob = vt + (size_t)(b * HKV_ + hk) * D_ * S_;

    short8 ks0, ks1, ks2, ks3, vs0, vs1, vs2, vs3;
    STAGE_LOAD(0);

    for (int t = 0; t <= qt; ++t) {
        const int k0 = t * 64;
        __syncthreads();   // previous tile's compute done reading LDS
        *(short8*)&k_lds[((tid >> 4)     ) * KPAD + (tid & 15) * 8] = ks0;
        *(short8*)&k_lds[((tid >> 4) + 16) * KPAD + (tid & 15) * 8] = ks1;
        *(short8*)&k_lds[((tid >> 4) + 32) * KPAD + (tid & 15) * 8] = ks2;
        *(short8*)&k_lds[((tid >> 4) + 48) * KPAD + (tid & 15) * 8] = ks3;
        *(short8*)&v_lds[((tid >> 3)     ) * VPAD + (tid & 7) * 8] = vs0;
        *(short8*)&v_lds[((tid >> 3) + 32) * VPAD + (tid & 7) * 8] = vs1;
        *(short8*)&v_lds[((tid >> 3) + 64) * VPAD + (tid & 7) * 8] = vs2;
        *(short8*)&v_lds[((tid >> 3) + 96) * VPAD + (tid & 7) * 8] = vs3;
        __syncthreads();   // staging visible
        if (t < qt) { STAGE_LOAD(k0 + 64); }   // prefetch next tile

        // ---- QK^T (swapped): lane owns q-row q_base+lr; k = f*16+lg*4+j ----
        f32x4 sc[4];
        #pragma unroll
        for (int f = 0; f < 4; ++f) sc[f] = (f32x4){0.f, 0.f, 0.f, 0.f};
        #pragma unroll
        for (int f = 0; f < 4; ++f)
            #pragma unroll
            for (int dc = 0; dc < 4; ++dc) {
                short8 kf = *(const short8*)&k_lds[(f * 16 + lr) * KPAD + dc * 32 + lg * 8];
                sc[f] = __builtin_amdgcn_mfma_f32_16x16x32_bf16(kf, qf[dc], sc[f], 0, 0, 0);
            }
        // ---- scale (+ causal mask only on the diagonal tile) ----
        float mxl = -1e30f;
        if (t == qt) {
            const int qpos = q_base + lr;
            #pragma unroll
            for (int f = 0; f < 4; ++f)
                #pragma unroll
                for (int j = 0; j < 4; ++j) {
                    int kpos = k0 + f * 16 + lg * 4 + j;
                    float s = sc[f][j] * SCALE2;
                    sc[f][j] = (kpos <= qpos) ? s : -1e30f;
                    mxl = fmaxf(mxl, sc[f][j]);
                }
        } else {
            #pragma unroll
            for (int f = 0; f < 4; ++f)
                #pragma unroll
                for (int j = 0; j < 4; ++j) {
                    sc[f][j] *= SCALE2;
                    mxl = fmaxf(mxl, sc[f][j]);
                }
        }
        // ---- online softmax, in-register (row = 4 lanes apart at xor 16/32) --
        mxl = fmaxf(mxl, __shfl_xor(mxl, 16));
        mxl = fmaxf(mxl, __shfl_xor(mxl, 32));
        float mnew = fmaxf(m_run, mxl);
        float corr = exp2f(m_run - mnew);
        m_run = mnew;
        float rs = 0.f;
        #pragma unroll
        for (int f = 0; f < 4; ++f)
            #pragma unroll
            for (int j = 0; j < 4; ++j) {
                sc[f][j] = exp2f(sc[f][j] - mnew);
                rs += sc[f][j];
            }
        rs += __shfl_xor(rs, 16);
        rs += __shfl_xor(rs, 32);
        l_run = l_run * corr + rs;
        #pragma unroll
        for (int cc = 0; cc < 8; ++cc)
            #pragma unroll
            for (int j = 0; j < 4; ++j) oacc[cc][j] *= corr;
        // ---- P -> B-operand fragment via shuffles (no LDS) ----
        unsigned pk[4][2];
        #pragma unroll
        for (int f = 0; f < 4; ++f) {
            pk[f][0] = (unsigned)f2bf(sc[f][0]) | ((unsigned)f2bf(sc[f][1]) << 16);
            pk[f][1] = (unsigned)f2bf(sc[f][2]) | ((unsigned)f2bf(sc[f][3]) << 16);
        }
        const int srcA = (lg & 1) * 32 + lr;
        const int srcB = srcA + 16;
        const bool hiF = ((lg >> 1) != 0);
        #pragma unroll
        for (int kh = 0; kh < 2; ++kh) {
            unsigned a0 = __shfl(pk[2 * kh][0], srcA), b0 = __shfl(pk[2 * kh + 1][0], srcA);
            unsigned a1 = __shfl(pk[2 * kh][1], srcA), b1 = __shfl(pk[2 * kh + 1][1], srcA);
            unsigned a2 = __shfl(pk[2 * kh][0], srcB), b2 = __shfl(pk[2 * kh + 1][0], srcB);
            unsigned a3 = __shfl(pk[2 * kh][1], srcB), b3 = __shfl(pk[2 * kh + 1][1], srcB);
            union { unsigned u[4]; short8 s8; } pf_;
            pf_.u[0] = hiF ? b0 : a0; pf_.u[1] = hiF ? b1 : a1;
            pf_.u[2] = hiF ? b2 : a2; pf_.u[3] = hiF ? b3 : a3;
            #pragma unroll
            for (int cc = 0; cc < 8; ++cc) {
                short8 vf = *(const short8*)&v_lds[(cc * 16 + lr) * VPAD + kh * 32 + lg * 8];
                oacc[cc] = __builtin_amdgcn_mfma_f32_16x16x32_bf16(vf, pf_.s8, oacc[cc], 0, 0, 0);
            }
        }
    }

    // lane holds O[q = q_base+lr][d = cc*16 + lg*4 + j] -> packed 8B stores
    {
        float inv = 1.0f / l_run;
        unsigned short* orow = o + (size_t)(b * S_ + q_base + lr) * DIM_ + h * D_ + lg * 4;
        #pragma unroll
        for (int cc = 0; cc < 8; ++cc) {
            union { unsigned short us[4]; unsigned long long u; } ov;
            #pragma unroll
            for (int j = 0; j < 4; ++j) ov.us[j] = f2bf(oacc[cc][j] * inv);
            *(unsigned long long*)(orow + cc * 16) = ov.u;
        }
    }
}

// ----------------------------------------------------------------------
extern "C" void kernel_launch(void* const* d_in, const int* in_sizes, int n_in,
                              void* d_out, int out_size, void* d_ws, size_t ws_size,
                              hipStream_t stream)
{
    const float* x  = (const float*)d_in[0];
    const float* Wq = (const float*)d_in[1];
    const float* Wk = (const float*)d_in[2];
    const float* Wv = (const float*)d_in[3];
    const float* Wo = (const float*)d_in[4];
    float* out = (float*)d_out;

    char* ws = (char*)d_ws;
    unsigned short* xb    = (unsigned short*)(ws);
    unsigned short* wqkvt = (unsigned short*)(ws + 16777216);
    unsigned short* wot   = (unsigned short*)(ws + 29360128);
    unsigned short* qkv   = (unsigned short*)(ws + 37748736);
    unsigned short* vt    = (unsigned short*)(ws + 62914560);
    unsigned short* attno = (unsigned short*)(ws + 67108864);

    // 1. x -> bf16
    k_convert<<<(BS_ * DIM_ / 4) / 256, 256, 0, stream>>>(x, xb, BS_ * DIM_ / 4);

    // 2. weight transposes into bf16 B^T panels
    k_transpose<<<dim3(DIM_ / 64, DIM_ / 64), 256, 0, stream>>>(Wq, wqkvt, DIM_, 2048);
    k_transpose<<<dim3(DIM_ / 64, 512 / 64), 256, 0, stream>>>(Wk, wqkvt + (size_t)2048 * 2048, DIM_, 512);
    k_transpose<<<dim3(DIM_ / 64, 512 / 64), 256, 0, stream>>>(Wv, wqkvt + (size_t)2560 * 2048, DIM_, 512);
    k_transpose<<<dim3(DIM_ / 64, DIM_ / 64), 256, 0, stream>>>(Wo, wot, 2048, 2048);

    // 3. QKV projection GEMM
    k_gemm_bt<unsigned short><<<(BS_ / 128) * (NQKV_ / 128), 256, 0, stream>>>(
        xb, wqkvt, qkv, BS_, NQKV_, DIM_);

    // 4. RoPE in-place on Q and K
    k_rope<<<dim3(5, BS_), 256, 0, stream>>>(qkv);

    // 5. V -> vt[(b,hk)][d][s]
    k_vtrans<<<dim3(S_ / 64, D_ / 64, B_ * HKV_), 256, 0, stream>>>(qkv, vt);

    // 6. flash attention (1024 balanced blocks, 4 blocks/CU)
    k_attn<<<dim3(1024), 256, 0, stream>>>(qkv, vt, attno);

    // 7. output GEMM
    k_gemm_bt<float><<<(BS_ / 128) * (DIM_ / 128), 256, 0, stream>>>(
        attno, wot, out, BS_, DIM_, DIM_);
}

// Round 14
// 379.533 us; speedup vs baseline: 1.0096x; 1.0096x over previous
//
#include <hip/hip_runtime.h>
#include <hip/hip_bf16.h>

#define B_    2
#define S_    2048
#define DIM_  2048
#define H_    16
#define HKV_  4
#define D_    128
#define NQKV_ 3072
#define BS_   (B_*S_)

typedef __attribute__((ext_vector_type(8))) short short8;
typedef __attribute__((ext_vector_type(4))) float f32x4;

__device__ __forceinline__ unsigned short f2bf(float f) {
    union { float f; unsigned u; } v; v.f = f;
    unsigned r = (v.u + 0x7fffu + ((v.u >> 16) & 1u)) >> 16;
    return (unsigned short)r;
}
__device__ __forceinline__ float bf2f(unsigned short h) {
    union { unsigned u; float f; } v; v.u = ((unsigned)h) << 16;
    return v.f;
}

// ---------------- convert x (fp32 -> bf16), vectorized ----------------
__global__ void k_convert(const float* __restrict__ in, unsigned short* __restrict__ out, int n4) {
    int i = blockIdx.x * blockDim.x + threadIdx.x;
    if (i >= n4) return;
    float4 v = ((const float4*)in)[i];
    union { unsigned short us[4]; unsigned long long u; } o;
    o.us[0] = f2bf(v.x); o.us[1] = f2bf(v.y); o.us[2] = f2bf(v.z); o.us[3] = f2bf(v.w);
    ((unsigned long long*)out)[i] = o.u;
}

// ------------- transpose fp32 [K][N] -> bf16 [N][K] -------------------
__global__ void k_transpose(const float* __restrict__ W, unsigned short* __restrict__ WT,
                            int K, int N) {
    __shared__ float tile[64][65];
    const int k0 = blockIdx.x * 64, n0 = blockIdx.y * 64;
    const int tx = threadIdx.x & 63, ty = threadIdx.x >> 6;
    #pragma unroll
    for (int i = 0; i < 64; i += 4)
        tile[ty + i][tx] = W[(size_t)(k0 + ty + i) * N + n0 + tx];
    __syncthreads();
    #pragma unroll
    for (int i = 0; i < 64; i += 4)
        WT[(size_t)(n0 + ty + i) * K + k0 + tx] = f2bf(tile[tx][ty + i]);
}

// ------------- GEMM: C[M][N] = A[M][K] * BT[N][K]^T  (bf16 MFMA) ------
// 128x128 tile, BK=64, 4 waves (2x2), 64x64/wave. XCD bijective swizzle.
template<typename OUT_T>
__global__ __launch_bounds__(256, 2)
void k_gemm_bt(const unsigned short* __restrict__ A,
               const unsigned short* __restrict__ BT,
               OUT_T* __restrict__ C, int M, int N, int K)
{
    __shared__ unsigned short lds_a[128 * 64];
    __shared__ unsigned short lds_b[128 * 64];
    const int tid  = threadIdx.x;
    const int nbn  = N >> 7;
    const int nwg  = gridDim.x;
    const int orig = blockIdx.x;
    const int q8   = nwg >> 3, r8 = nwg & 7;
    const int xcd  = orig & 7, lid = orig >> 3;
    const int wgid = (xcd < r8 ? xcd * (q8 + 1) : r8 * (q8 + 1) + (xcd - r8) * q8) + lid;
    const int bm   = wgid / nbn, bn = wgid % nbn;
    const int row0 = bm << 7, col0 = bn << 7;
    const int lane = tid & 63, wave = tid >> 6;
    const int wr = wave >> 1, wc = wave & 1;
    const int lg = lane >> 4, lr = lane & 15;

    f32x4 acc[4][4] = {};

    for (int kt = 0; kt < K; kt += 64) {
        __syncthreads();
        #pragma unroll
        for (int issue = 0; issue < 4; ++issue) {
            int e = issue * 2048 + wave * 512 + lane * 8;
            int r = e >> 6, kk = e & 63;
            const unsigned short* srcA = A  + (size_t)(row0 + r) * K + kt + kk;
            const unsigned short* srcB = BT + (size_t)(col0 + r) * K + kt + kk;
            unsigned short* dstA = lds_a + issue * 2048 + wave * 512;
            unsigned short* dstB = lds_b + issue * 2048 + wave * 512;
            __builtin_amdgcn_global_load_lds(
                (const __attribute__((address_space(1))) void*)srcA,
                (__attribute__((address_space(3))) void*)dstA, 16, 0, 0);
            __builtin_amdgcn_global_load_lds(
                (const __attribute__((address_space(1))) void*)srcB,
                (__attribute__((address_space(3))) void*)dstB, 16, 0, 0);
        }
        __syncthreads();
        #pragma unroll
        for (int kc = 0; kc < 2; ++kc) {
            short8 af[4], bf[4];
            #pragma unroll
            for (int m = 0; m < 4; ++m)
                af[m] = *(const short8*)&lds_a[(wr * 64 + m * 16 + lr) * 64 + kc * 32 + lg * 8];
            #pragma unroll
            for (int n = 0; n < 4; ++n)
                bf[n] = *(const short8*)&lds_b[(wc * 64 + n * 16 + lr) * 64 + kc * 32 + lg * 8];
            #pragma unroll
            for (int m = 0; m < 4; ++m)
                #pragma unroll
                for (int n = 0; n < 4; ++n)
                    acc[m][n] = __builtin_amdgcn_mfma_f32_16x16x32_bf16(af[m], bf[n], acc[m][n], 0, 0, 0);
        }
    }

    #pragma unroll
    for (int m = 0; m < 4; ++m)
        #pragma unroll
        for (int n = 0; n < 4; ++n)
            #pragma unroll
            for (int j = 0; j < 4; ++j) {
                int row = row0 + wr * 64 + m * 16 + lg * 4 + j;
                int col = col0 + wc * 64 + n * 16 + lr;
                if constexpr (sizeof(OUT_T) == 2)
                    C[(size_t)row * N + col] = (OUT_T)f2bf(acc[m][n][j]);
                else
                    C[(size_t)row * N + col] = (OUT_T)acc[m][n][j];
            }
}

// ------------------------- RoPE on Q and K (in-place) -----------------
__global__ void k_rope(unsigned short* __restrict__ qkv) {
    const int pair = blockIdx.x * 256 + threadIdx.x;
    const int row  = blockIdx.y;
    const int s    = row & (S_ - 1);
    const int col  = pair * 2;
    const int t    = (col & 127) >> 1;
    const float theta = exp2f(-((float)(2 * t) / 128.0f) * 9.965784284662087f);
    const float ang = (float)s * theta;
    const float sn = sinf(ang), cs = cosf(ang);
    unsigned short* p = qkv + (size_t)row * NQKV_ + col;
    float x1 = bf2f(p[0]), x2 = bf2f(p[1]);
    p[0] = f2bf(x1 * cs - x2 * sn);
    p[1] = f2bf(x1 * sn + x2 * cs);
}

// --------- transpose V out of qkv: vt[(b*4+hk)][d][s] (bf16) ----------
__global__ void k_vtrans(const unsigned short* __restrict__ qkv, unsigned short* __restrict__ vt) {
    __shared__ unsigned short tile[64][65];
    const int s0 = blockIdx.x * 64;
    const int d0 = blockIdx.y * 64;
    const int bh = blockIdx.z;
    const int b = bh >> 2, hk = bh & 3;
    const int tx = threadIdx.x & 63, ty = threadIdx.x >> 6;
    #pragma unroll
    for (int i = 0; i < 64; i += 4)
        tile[i + ty][tx] = qkv[(size_t)(b * S_ + s0 + i + ty) * NQKV_ + (DIM_ + 512) + hk * D_ + d0 + tx];
    __syncthreads();
    #pragma unroll
    for (int i = 0; i < 64; i += 4)
        vt[((size_t)bh * D_ + d0 + i + ty) * S_ + s0 + tx] = tile[tx][i + ty];
}

// --------------------------- flash attention --------------------------
// grid 1024 linear; 4 waves/block; one 64-row q-tile per block.
// Bijective L->(qt,h,b) with w-flip so co-resident blocks pair (qt,31-qt).
// launch_bounds(256,3): VGPR cap ~170 -> no spill (R13's (256,4) forced a
// 64-VGPR allocation with 128MB of scratch writes). If alloc <=128 the HW
// still runs 4 blocks/CU; worst case 3.
#define KPAD 136   // 128 + 8
#define VPAD 72    // 64 + 8
#define SCALE2 0.12751739f   // (1/sqrt(128)) * log2(e)

#define STAGE_LOAD(K0) do {                                                                    \
    ks0 = *(const short8*)(kglob + (size_t)((K0) + (tid >> 4)) * NQKV_ + (tid & 15) * 8);      \
    ks1 = *(const short8*)(kglob + (size_t)((K0) + 16 + (tid >> 4)) * NQKV_ + (tid & 15) * 8); \
    ks2 = *(const short8*)(kglob + (size_t)((K0) + 32 + (tid >> 4)) * NQKV_ + (tid & 15) * 8); \
    ks3 = *(const short8*)(kglob + (size_t)((K0) + 48 + (tid >> 4)) * NQKV_ + (tid & 15) * 8); \
    vs0 = *(const short8*)(vglob + (size_t)(tid >> 3) * S_ + (K0) + (tid & 7) * 8);            \
    vs1 = *(const short8*)(vglob + (size_t)(32 + (tid >> 3)) * S_ + (K0) + (tid & 7) * 8);     \
    vs2 = *(const short8*)(vglob + (size_t)(64 + (tid >> 3)) * S_ + (K0) + (tid & 7) * 8);     \
    vs3 = *(const short8*)(vglob + (size_t)(96 + (tid >> 3)) * S_ + (K0) + (tid & 7) * 8);     \
} while (0)

__global__ __launch_bounds__(256, 3)
void k_attn(const unsigned short* __restrict__ qkv,
            const unsigned short* __restrict__ vt,
            unsigned short* __restrict__ o)
{
    __shared__ unsigned short k_lds[64 * KPAD];    // 17408 B
    __shared__ unsigned short v_lds[128 * VPAD];   // 18432 B

    const int L   = blockIdx.x;
    const int w4  = L >> 8;                  // 0..3
    const int c   = L & 255;
    const int qt0 = c & 31;
    const int hb  = (c >> 5) | (w4 << 3);    // 0..31
    const int h   = hb & 15, b = hb >> 4;
    const int qt  = (w4 & 1) ? (31 - qt0) : qt0;   // pair (qt,31-qt) per CU
    const int hk  = h >> 2;

    const int tid = threadIdx.x;
    const int lane = tid & 63, wave = tid >> 6;    // 4 waves
    const int lg = lane >> 4, lr = lane & 15;
    const int q_base = qt * 64 + wave * 16;

    // Q fragments (B-operand of swapped QK^T)
    short8 qf[4];
    {
        const unsigned short* qrow = qkv + (size_t)(b * S_ + q_base + lr) * NQKV_ + h * D_;
        #pragma unroll
        for (int dc = 0; dc < 4; ++dc)
            qf[dc] = *(const short8*)(qrow + dc * 32 + lg * 8);
    }

    float m_run = -1e30f, l_run = 0.f;
    f32x4 oacc[8] = {};

    const unsigned short* kglob = qkv + (size_t)(b * S_) * NQKV_ + DIM_ + hk * D_;
    const unsigned short* vglob = vt + (size_t)(b * HKV_ + hk) * D_ * S_;

    short8 ks0, ks1, ks2, ks3, vs0, vs1, vs2, vs3;
    STAGE_LOAD(0);

    for (int t = 0; t <= qt; ++t) {
        const int k0 = t * 64;
        __syncthreads();   // previous tile's compute done reading LDS
        *(short8*)&k_lds[((tid >> 4)     ) * KPAD + (tid & 15) * 8] = ks0;
        *(short8*)&k_lds[((tid >> 4) + 16) * KPAD + (tid & 15) * 8] = ks1;
        *(short8*)&k_lds[((tid >> 4) + 32) * KPAD + (tid & 15) * 8] = ks2;
        *(short8*)&k_lds[((tid >> 4) + 48) * KPAD + (tid & 15) * 8] = ks3;
        *(short8*)&v_lds[((tid >> 3)     ) * VPAD + (tid & 7) * 8] = vs0;
        *(short8*)&v_lds[((tid >> 3) + 32) * VPAD + (tid & 7) * 8] = vs1;
        *(short8*)&v_lds[((tid >> 3) + 64) * VPAD + (tid & 7) * 8] = vs2;
        *(short8*)&v_lds[((tid >> 3) + 96) * VPAD + (tid & 7) * 8] = vs3;
        __syncthreads();   // staging visible
        if (t < qt) { STAGE_LOAD(k0 + 64); }   // prefetch next tile

        // ---- QK^T (swapped): lane owns q-row q_base+lr; k = f*16+lg*4+j ----
        f32x4 sc[4];
        #pragma unroll
        for (int f = 0; f < 4; ++f) sc[f] = (f32x4){0.f, 0.f, 0.f, 0.f};
        #pragma unroll
        for (int f = 0; f < 4; ++f)
            #pragma unroll
            for (int dc = 0; dc < 4; ++dc) {
                short8 kf = *(const short8*)&k_lds[(f * 16 + lr) * KPAD + dc * 32 + lg * 8];
                sc[f] = __builtin_amdgcn_mfma_f32_16x16x32_bf16(kf, qf[dc], sc[f], 0, 0, 0);
            }
        // ---- scale (+ causal mask only on the diagonal tile) ----
        float mxl = -1e30f;
        if (t == qt) {
            const int qpos = q_base + lr;
            #pragma unroll
            for (int f = 0; f < 4; ++f)
                #pragma unroll
                for (int j = 0; j < 4; ++j) {
                    int kpos = k0 + f * 16 + lg * 4 + j;
                    float s = sc[f][j] * SCALE2;
                    sc[f][j] = (kpos <= qpos) ? s : -1e30f;
                    mxl = fmaxf(mxl, sc[f][j]);
                }
        } else {
            #pragma unroll
            for (int f = 0; f < 4; ++f)
                #pragma unroll
                for (int j = 0; j < 4; ++j) {
                    sc[f][j] *= SCALE2;
                    mxl = fmaxf(mxl, sc[f][j]);
                }
        }
        // ---- online softmax, in-register (row = 4 lanes apart at xor 16/32) --
        mxl = fmaxf(mxl, __shfl_xor(mxl, 16));
        mxl = fmaxf(mxl, __shfl_xor(mxl, 32));
        float mnew = fmaxf(m_run, mxl);
        float corr = exp2f(m_run - mnew);
        m_run = mnew;
        float rs = 0.f;
        #pragma unroll
        for (int f = 0; f < 4; ++f)
            #pragma unroll
            for (int j = 0; j < 4; ++j) {
                sc[f][j] = exp2f(sc[f][j] - mnew);
                rs += sc[f][j];
            }
        rs += __shfl_xor(rs, 16);
        rs += __shfl_xor(rs, 32);
        l_run = l_run * corr + rs;
        #pragma unroll
        for (int cc = 0; cc < 8; ++cc)
            #pragma unroll
            for (int j = 0; j < 4; ++j) oacc[cc][j] *= corr;
        // ---- P -> B-operand fragment via shuffles (no LDS) ----
        unsigned pk[4][2];
        #pragma unroll
        for (int f = 0; f < 4; ++f) {
            pk[f][0] = (unsigned)f2bf(sc[f][0]) | ((unsigned)f2bf(sc[f][1]) << 16);
            pk[f][1] = (unsigned)f2bf(sc[f][2]) | ((unsigned)f2bf(sc[f][3]) << 16);
        }
        const int srcA = (lg & 1) * 32 + lr;
        const int srcB = srcA + 16;
        const bool hiF = ((lg >> 1) != 0);
        #pragma unroll
        for (int kh = 0; kh < 2; ++kh) {
            unsigned a0 = __shfl(pk[2 * kh][0], srcA), b0 = __shfl(pk[2 * kh + 1][0], srcA);
            unsigned a1 = __shfl(pk[2 * kh][1], srcA), b1 = __shfl(pk[2 * kh + 1][1], srcA);
            unsigned a2 = __shfl(pk[2 * kh][0], srcB), b2 = __shfl(pk[2 * kh + 1][0], srcB);
            unsigned a3 = __shfl(pk[2 * kh][1], srcB), b3 = __shfl(pk[2 * kh + 1][1], srcB);
            union { unsigned u[4]; short8 s8; } pf_;
            pf_.u[0] = hiF ? b0 : a0; pf_.u[1] = hiF ? b1 : a1;
            pf_.u[2] = hiF ? b2 : a2; pf_.u[3] = hiF ? b3 : a3;
            #pragma unroll
            for (int cc = 0; cc < 8; ++cc) {
                short8 vf = *(const short8*)&v_lds[(cc * 16 + lr) * VPAD + kh * 32 + lg * 8];
                oacc[cc] = __builtin_amdgcn_mfma_f32_16x16x32_bf16(vf, pf_.s8, oacc[cc], 0, 0, 0);
            }
        }
    }

    // lane holds O[q = q_base+lr][d = cc*16 + lg*4 + j] -> packed 8B stores
    {
        float inv = 1.0f / l_run;
        unsigned short* orow = o + (size_t)(b * S_ + q_base + lr) * DIM_ + h * D_ + lg * 4;
        #pragma unroll
        for (int cc = 0; cc < 8; ++cc) {
            union { unsigned short us[4]; unsigned long long u; } ov;
            #pragma unroll
            for (int j = 0; j < 4; ++j) ov.us[j] = f2bf(oacc[cc][j] * inv);
            *(unsigned long long*)(orow + cc * 16) = ov.u;
        }
    }
}

// ----------------------------------------------------------------------
extern "C" void kernel_launch(void* const* d_in, const int* in_sizes, int n_in,
                              void* d_out, int out_size, void* d_ws, size_t ws_size,
                              hipStream_t stream)
{
    const float* x  = (const float*)d_in[0];
    const float* Wq = (const float*)d_in[1];
    const float* Wk = (const float*)d_in[2];
    const float* Wv = (const float*)d_in[3];
    const float* Wo = (const float*)d_in[4];
    float* out = (float*)d_out;

    char* ws = (char*)d_ws;
    unsigned short* xb    = (unsigned short*)(ws);
    unsigned short* wqkvt = (unsigned short*)(ws + 16777216);
    unsigned short* wot   = (unsigned short*)(ws + 29360128);
    unsigned short* qkv   = (unsigned short*)(ws + 37748736);
    unsigned short* vt    = (unsigned short*)(ws + 62914560);
    unsigned short* attno = (unsigned short*)(ws + 67108864);

    // 1. x -> bf16
    k_convert<<<(BS_ * DIM_ / 4) / 256, 256, 0, stream>>>(x, xb, BS_ * DIM_ / 4);

    // 2. weight transposes into bf16 B^T panels
    k_transpose<<<dim3(DIM_ / 64, DIM_ / 64), 256, 0, stream>>>(Wq, wqkvt, DIM_, 2048);
    k_transpose<<<dim3(DIM_ / 64, 512 / 64), 256, 0, stream>>>(Wk, wqkvt + (size_t)2048 * 2048, DIM_, 512);
    k_transpose<<<dim3(DIM_ / 64, 512 / 64), 256, 0, stream>>>(Wv, wqkvt + (size_t)2560 * 2048, DIM_, 512);
    k_transpose<<<dim3(DIM_ / 64, DIM_ / 64), 256, 0, stream>>>(Wo, wot, 2048, 2048);

    // 3. QKV projection GEMM
    k_gemm_bt<unsigned short><<<(BS_ / 128) * (NQKV_ / 128), 256, 0, stream>>>(
        xb, wqkvt, qkv, BS_, NQKV_, DIM_);

    // 4. RoPE in-place on Q and K
    k_rope<<<dim3(5, BS_), 256, 0, stream>>>(qkv);

    // 5. V -> vt[(b,hk)][d][s]
    k_vtrans<<<dim3(S_ / 64, D_ / 64, B_ * HKV_), 256, 0, stream>>>(qkv, vt);

    // 6. flash attention (1024 balanced blocks, no-spill register budget)
    k_attn<<<dim3(1024), 256, 0, stream>>>(qkv, vt, attno);

    // 7. output GEMM
    k_gemm_bt<float><<<(BS_ / 128) * (DIM_ / 128), 256, 0, stream>>>(
        attno, wot, out, BS_, DIM_, DIM_);
}